// Round 8
// baseline (246.753 us; speedup 1.0000x reference)
//
#include <hip/hip_runtime.h>

// Problem constants (shapes fixed by setup_inputs): nw_out [N=4, C=19, H=512, W=1024] fp32.
#define N_IMG 4
#define C_CLS 19
#define HW    (512 * 1024)          // per-image, per-channel plane
#define NPIX  (N_IMG * HW)          // 2,097,152 pixels
#define VPIX2 (NPIX / 2)            // 1,048,576 float2 pixel-groups
#define NBLK  (VPIX2 / 256)         // 4,096 blocks
#define NCOL  (2 * C_CLS)           // 38 scratch columns (19 sums + 19 counts)
#define IW    0.2f

typedef float f2 __attribute__((ext_vector_type(2)));
typedef float f4 __attribute__((ext_vector_type(4)));

// ---------------------------------------------------------------------------
// MEASUREMENT ROUND. r5/r6/r7 (three structurally different main_pass
// variants: 2x occupancy span, 2x load width, 2x grid) all landed within
// 1.8 us total — so either main_pass is ~70 us and none of those levers
// matter, or it is ~25 us and the total is harness-fixed. The top-5 cutoff
// (93 us fills) hides it. This round launches the IDENTICAL main_pass twice:
// scratch is a pure overwrite, so the output is byte-identical (absmax 0)
// and the total's delta vs r7's 220.1 IS main_pass's true marginal cost.
//   total ~250  -> main_pass ~30 us: at floor, declare roofline next round.
//   total ~290  -> main_pass ~70 us: attack the read path with ~45 us headroom.
// ---------------------------------------------------------------------------
__global__ __launch_bounds__(256) void main_pass(const float* __restrict__ x,
                                                 float* __restrict__ scratch) {
    __shared__ float s_sum[C_CLS];
    __shared__ float s_cnt[C_CLS];
    const int t = threadIdx.x;
    if (t < C_CLS) { s_sum[t] = 0.0f; s_cnt[t] = 0.0f; }
    __syncthreads();

    // f2 pixel-group index; grid exactly covers VPIX2 (4096 blocks * 256).
    const int v   = blockIdx.x * 256 + t;
    const int n   = v >> 18;                 // HW/2 = 262144 = 2^18
    const int hw2 = v & (262144 - 1);
    const float* base = x + (size_t)n * C_CLS * HW + (size_t)hw2 * 2;

    // Burst-load all 19 channels x 2 pixels (19 independent dwordx2).
    f2 val[C_CLS];
#pragma unroll
    for (int c = 0; c < C_CLS; ++c)
        val[c] = *(const f2*)(base + (size_t)c * HW);

    // Pin the burst: nothing crosses; every val[c] forced live in VGPRs here.
    __builtin_amdgcn_sched_barrier(0);
#pragma unroll
    for (int c = 0; c < C_CLS; ++c)
        asm volatile("" : "+v"(val[c]));

#pragma unroll
    for (int j = 0; j < 2; ++j) {
        // row max via 5-deep tree (compiler may fuse pairs into v_max3)
        float a0 = fmaxf(val[0][j],  val[1][j]);
        float a1 = fmaxf(val[2][j],  val[3][j]);
        float a2 = fmaxf(val[4][j],  val[5][j]);
        float a3 = fmaxf(val[6][j],  val[7][j]);
        float a4 = fmaxf(val[8][j],  val[9][j]);
        float a5 = fmaxf(val[10][j], val[11][j]);
        float a6 = fmaxf(val[12][j], val[13][j]);
        float a7 = fmaxf(val[14][j], val[15][j]);
        float a8 = fmaxf(val[16][j], val[17][j]);
        float b0 = fmaxf(a0, a1);
        float b1 = fmaxf(a2, a3);
        float b2 = fmaxf(a4, a5);
        float b3 = fmaxf(a6, a7);
        float b4 = fmaxf(a8, val[18][j]);
        float m  = fmaxf(fmaxf(fmaxf(b0, b1), fmaxf(b2, b3)), b4);

        // first-max argmax: smallest c with val[c] == m (fmax returns an
        // input bitwise; no NaNs in input; ties pick smallest index)
        int am = 18;
#pragma unroll
        for (int c = 17; c >= 0; --c)
            am = (val[c][j] == m) ? c : am;

        // l = sum exp(x-m), q = sum exp(x-m)^2, even/odd split accumulators
        float l0 = 0.0f, l1 = 0.0f, q0 = 0.0f, q1 = 0.0f;
#pragma unroll
        for (int c = 0; c < C_CLS; c += 2) {
            float e = __expf(val[c][j] - m);
            l0 += e; q0 += e * e;
        }
#pragma unroll
        for (int c = 1; c < C_CLS; c += 2) {
            float e = __expf(val[c][j] - m);
            l1 += e; q1 += e * e;
        }
        float l = l0 + l1, q = q0 + q1;
        float s = q / (l * l);
        atomicAdd(&s_sum[am], s);
        atomicAdd(&s_cnt[am], 1.0f);   // exact: integer-valued fp32 < 2^24
    }

    __syncthreads();
    // Column-major scratch[c][b]: pure overwrite, zero contention, no atomics.
    if (t < NCOL)
        scratch[t * NBLK + blockIdx.x] = (t < C_CLS) ? s_sum[t] : s_cnt[t - C_CLS];
}

// ---------------------------------------------------------------------------
// Kernel 2: parallel column reduction — 38 blocks, one per scratch column.
// ---------------------------------------------------------------------------
__global__ __launch_bounds__(256) void colsum(const float* __restrict__ scratch,
                                              float* __restrict__ tot) {
    __shared__ float wsum[4];
    const int c    = blockIdx.x;             // 0..37
    const int t    = threadIdx.x;
    const int wave = t >> 6;
    const int lane = t & 63;

    const f4* col = (const f4*)(scratch + (size_t)c * NBLK);  // 1024 f4
    float acc = 0.0f;
#pragma unroll
    for (int k = 0; k < 4; ++k) {
        f4 vv = col[k * 256 + t];
        acc += (vv[0] + vv[1]) + (vv[2] + vv[3]);
    }
#pragma unroll
    for (int off = 32; off > 0; off >>= 1)
        acc += __shfl_down(acc, off);
    if (lane == 0) wsum[wave] = acc;
    __syncthreads();
    if (t == 0)
        tot[c] = (wsum[0] + wsum[1]) + (wsum[2] + wsum[3]);
}

// ---------------------------------------------------------------------------
// Kernel 3: den_c = max(hist^0.2 * Np^0.8, 1); out = -sum_c(tot[c]/den_c)/(N*C)
// ---------------------------------------------------------------------------
__global__ void finalize(const float* __restrict__ tot,
                         float* __restrict__ out) {
    const int t = threadIdx.x;   // one wave of 64
    float vsum = 0.0f;
    if (t < C_CLS) {
        const float scale = powf((float)NPIX, 1.0f - IW);   // Np^0.8
        float den = fmaxf(powf(tot[C_CLS + t], IW) * scale, 1.0f);
        vsum = tot[t] / den;
    }
#pragma unroll
    for (int off = 32; off > 0; off >>= 1)
        vsum += __shfl_down(vsum, off);
    if (t == 0)
        out[0] = -vsum / (float)(N_IMG * C_CLS);
}

extern "C" void kernel_launch(void* const* d_in, const int* in_sizes, int n_in,
                              void* d_out, int out_size, void* d_ws, size_t ws_size,
                              hipStream_t stream) {
    const float* x = (const float*)d_in[0];
    float* scratch = (float*)d_ws;            // [38][4096] floats = 622 KB
    float* tot     = scratch + (size_t)NCOL * NBLK;   // [38] floats

    // Launched TWICE on purpose (slope measurement; see header comment).
    main_pass<<<NBLK, 256, 0, stream>>>(x, scratch);
    main_pass<<<NBLK, 256, 0, stream>>>(x, scratch);
    colsum<<<NCOL, 256, 0, stream>>>(scratch, tot);
    finalize<<<1, 64, 0, stream>>>(tot, (float*)d_out);
}

// Round 9
// 220.426 us; speedup vs baseline: 1.1194x; 1.1194x over previous
//
#include <hip/hip_runtime.h>

// Problem constants (shapes fixed by setup_inputs): nw_out [N=4, C=19, H=512, W=1024] fp32.
#define N_IMG 4
#define C_CLS 19
#define HW    (512 * 1024)          // per-image, per-channel plane
#define NPIX  (N_IMG * HW)          // 2,097,152 pixels
#define VPIX2 (NPIX / 2)            // 1,048,576 float2 pixel-groups
#define NBLK  (VPIX2 / 256)         // 4,096 blocks
#define NCOL  (2 * C_CLS)           // 38 scratch columns (19 sums + 19 counts)
#define IW    0.2f

typedef float f2 __attribute__((ext_vector_type(2)));
typedef float f4 __attribute__((ext_vector_type(4)));

// ---------------------------------------------------------------------------
// Kernel 1: single full pass over the input. FINAL FORM (r7, 220.1 us total).
//
// r8 slope measurement (double-launch): marginal cost of this kernel is
// ~26.6 us against a ~24-25 us streaming floor (159.4 MB, ~half L3-resident,
// 6.9 TB/s fill-proven rate; ~7 us VALU + ~1 us exp fully overlapped).
// It is at its memory roofline — r5/r6/r7's insensitivity to occupancy/
// load-width/grid (2-4x swings, <1% total delta) is explained: all variants
// were already floor-bound. Remaining total is ~193 us of harness-fixed
// poison-fill/reset dispatches visible in the rocprof top-5.
//
// Structure: pinned 19-load burst (r2-vs-r4: without the sched_barrier +
// asm "+v" pin the compiler sinks loads into a serial chain, 4x slower),
// 5-deep max tree, equality-select first-max argmax (jnp.argmax semantics),
// even/odd-split l/q accumulation, LDS class histogram, zero-contention
// column-major scratch stores (r5: removed the 78K-lane global atomic tail).
// ---------------------------------------------------------------------------
__global__ __launch_bounds__(256) void main_pass(const float* __restrict__ x,
                                                 float* __restrict__ scratch) {
    __shared__ float s_sum[C_CLS];
    __shared__ float s_cnt[C_CLS];
    const int t = threadIdx.x;
    if (t < C_CLS) { s_sum[t] = 0.0f; s_cnt[t] = 0.0f; }
    __syncthreads();

    // f2 pixel-group index; grid exactly covers VPIX2 (4096 blocks * 256).
    const int v   = blockIdx.x * 256 + t;
    const int n   = v >> 18;                 // HW/2 = 262144 = 2^18
    const int hw2 = v & (262144 - 1);
    const float* base = x + (size_t)n * C_CLS * HW + (size_t)hw2 * 2;

    // Burst-load all 19 channels x 2 pixels (19 independent dwordx2).
    f2 val[C_CLS];
#pragma unroll
    for (int c = 0; c < C_CLS; ++c)
        val[c] = *(const f2*)(base + (size_t)c * HW);

    // Pin the burst: nothing crosses; every val[c] forced live in VGPRs here.
    __builtin_amdgcn_sched_barrier(0);
#pragma unroll
    for (int c = 0; c < C_CLS; ++c)
        asm volatile("" : "+v"(val[c]));

#pragma unroll
    for (int j = 0; j < 2; ++j) {
        // row max via 5-deep tree (compiler may fuse pairs into v_max3)
        float a0 = fmaxf(val[0][j],  val[1][j]);
        float a1 = fmaxf(val[2][j],  val[3][j]);
        float a2 = fmaxf(val[4][j],  val[5][j]);
        float a3 = fmaxf(val[6][j],  val[7][j]);
        float a4 = fmaxf(val[8][j],  val[9][j]);
        float a5 = fmaxf(val[10][j], val[11][j]);
        float a6 = fmaxf(val[12][j], val[13][j]);
        float a7 = fmaxf(val[14][j], val[15][j]);
        float a8 = fmaxf(val[16][j], val[17][j]);
        float b0 = fmaxf(a0, a1);
        float b1 = fmaxf(a2, a3);
        float b2 = fmaxf(a4, a5);
        float b3 = fmaxf(a6, a7);
        float b4 = fmaxf(a8, val[18][j]);
        float m  = fmaxf(fmaxf(fmaxf(b0, b1), fmaxf(b2, b3)), b4);

        // first-max argmax: smallest c with val[c] == m (fmax returns an
        // input bitwise; no NaNs in input; ties pick smallest index)
        int am = 18;
#pragma unroll
        for (int c = 17; c >= 0; --c)
            am = (val[c][j] == m) ? c : am;

        // l = sum exp(x-m), q = sum exp(x-m)^2, even/odd split accumulators
        float l0 = 0.0f, l1 = 0.0f, q0 = 0.0f, q1 = 0.0f;
#pragma unroll
        for (int c = 0; c < C_CLS; c += 2) {
            float e = __expf(val[c][j] - m);
            l0 += e; q0 += e * e;
        }
#pragma unroll
        for (int c = 1; c < C_CLS; c += 2) {
            float e = __expf(val[c][j] - m);
            l1 += e; q1 += e * e;
        }
        float l = l0 + l1, q = q0 + q1;
        float s = q / (l * l);
        atomicAdd(&s_sum[am], s);
        atomicAdd(&s_cnt[am], 1.0f);   // exact: integer-valued fp32 < 2^24
    }

    __syncthreads();
    // Column-major scratch[c][b]: pure overwrite, zero contention, no atomics.
    if (t < NCOL)
        scratch[t * NBLK + blockIdx.x] = (t < C_CLS) ? s_sum[t] : s_cnt[t - C_CLS];
}

// ---------------------------------------------------------------------------
// Kernel 2: parallel column reduction — 38 blocks, one per scratch column.
// ---------------------------------------------------------------------------
__global__ __launch_bounds__(256) void colsum(const float* __restrict__ scratch,
                                              float* __restrict__ tot) {
    __shared__ float wsum[4];
    const int c    = blockIdx.x;             // 0..37
    const int t    = threadIdx.x;
    const int wave = t >> 6;
    const int lane = t & 63;

    const f4* col = (const f4*)(scratch + (size_t)c * NBLK);  // 1024 f4
    float acc = 0.0f;
#pragma unroll
    for (int k = 0; k < 4; ++k) {
        f4 vv = col[k * 256 + t];
        acc += (vv[0] + vv[1]) + (vv[2] + vv[3]);
    }
#pragma unroll
    for (int off = 32; off > 0; off >>= 1)
        acc += __shfl_down(acc, off);
    if (lane == 0) wsum[wave] = acc;
    __syncthreads();
    if (t == 0)
        tot[c] = (wsum[0] + wsum[1]) + (wsum[2] + wsum[3]);
}

// ---------------------------------------------------------------------------
// Kernel 3: den_c = max(hist^0.2 * Np^0.8, 1); out = -sum_c(tot[c]/den_c)/(N*C)
// ---------------------------------------------------------------------------
__global__ void finalize(const float* __restrict__ tot,
                         float* __restrict__ out) {
    const int t = threadIdx.x;   // one wave of 64
    float vsum = 0.0f;
    if (t < C_CLS) {
        const float scale = powf((float)NPIX, 1.0f - IW);   // Np^0.8
        float den = fmaxf(powf(tot[C_CLS + t], IW) * scale, 1.0f);
        vsum = tot[t] / den;
    }
#pragma unroll
    for (int off = 32; off > 0; off >>= 1)
        vsum += __shfl_down(vsum, off);
    if (t == 0)
        out[0] = -vsum / (float)(N_IMG * C_CLS);
}

extern "C" void kernel_launch(void* const* d_in, const int* in_sizes, int n_in,
                              void* d_out, int out_size, void* d_ws, size_t ws_size,
                              hipStream_t stream) {
    const float* x = (const float*)d_in[0];
    float* scratch = (float*)d_ws;            // [38][4096] floats = 622 KB
    float* tot     = scratch + (size_t)NCOL * NBLK;   // [38] floats

    main_pass<<<NBLK, 256, 0, stream>>>(x, scratch);
    colsum<<<NCOL, 256, 0, stream>>>(scratch, tot);
    finalize<<<1, 64, 0, stream>>>(tot, (float*)d_out);
}